// Round 1
// baseline (590.536 us; speedup 1.0000x reference)
//
#include <hip/hip_runtime.h>

// SpatialAttention (QKNorm, no 1/sqrt(d)): B=1,T=8,S=1024,HID=1152,H=16,D=72
// Pipeline: cvt x->bf16 | W^T bf16 | GEMM1->q | rmsnorm q | GEMM2->k,v |
//           rmsnorm k | zero v-pads | flash attn | GEMM3 -> f32 out

typedef __attribute__((ext_vector_type(4))) short s16x4;
typedef __attribute__((ext_vector_type(8))) short s16x8;
typedef __attribute__((ext_vector_type(4))) float f32x4;

__device__ __forceinline__ unsigned short f2b(float x) {
  unsigned u = __float_as_uint(x);
  u += 0x7FFFu + ((u >> 16) & 1u);
  return (unsigned short)(u >> 16);
}
__device__ __forceinline__ float b2f(unsigned short u) {
  return __uint_as_float(((unsigned)u) << 16);
}

// ---------------- x -> bf16 ----------------
__global__ __launch_bounds__(256) void cvt_bf16_kernel(const float* __restrict__ in,
                                                       unsigned short* __restrict__ out,
                                                       int n8) {
  int i = blockIdx.x * 256 + threadIdx.x;
  if (i >= n8) return;
  const float4* p = (const float4*)(in + (size_t)i * 8);
  float4 a = p[0], b = p[1];
  s16x8 r;
  r[0] = (short)f2b(a.x); r[1] = (short)f2b(a.y); r[2] = (short)f2b(a.z); r[3] = (short)f2b(a.w);
  r[4] = (short)f2b(b.x); r[5] = (short)f2b(b.y); r[6] = (short)f2b(b.z); r[7] = (short)f2b(b.w);
  *(s16x8*)(out + (size_t)i * 8) = r;
}

// ---------------- W [K][N] f32 -> WT [N][K] bf16 ----------------
__global__ __launch_bounds__(256) void transpose_cvt_kernel(const float* __restrict__ W,
                                                            unsigned short* __restrict__ WT,
                                                            int K, int N) {
  __shared__ float tile[32][33];
  int n0 = blockIdx.x * 32, k0 = blockIdx.y * 32;
  int tx = threadIdx.x, ty = threadIdx.y;
#pragma unroll
  for (int i = 0; i < 4; i++)
    tile[ty + i * 8][tx] = W[(size_t)(k0 + ty + i * 8) * N + n0 + tx];
  __syncthreads();
#pragma unroll
  for (int i = 0; i < 4; i++)
    WT[(size_t)(n0 + ty + i * 8) * K + k0 + tx] = f2b(tile[tx][ty + i * 8]);
}

// ---------------- GEMM: C[M,N] = A[M,K] @ BT[N,K]^T (+bias) ----------------
// MODE 0: outF f32 row-major.  MODE 1: q -> outK bf16 [th][s][96].
// MODE 2: kv -> outK (col<1152), outV (col>=1152), bf16 [th][s][96].
template <int MODE>
__global__ __launch_bounds__(256) void gemm_bt_kernel(const unsigned short* __restrict__ A,
                                                      const unsigned short* __restrict__ BT,
                                                      const float* __restrict__ bias, int N,
                                                      float* __restrict__ outF,
                                                      unsigned short* __restrict__ outK,
                                                      unsigned short* __restrict__ outV) {
  constexpr int K = 1152;
  __shared__ unsigned short As[128][40];
  __shared__ unsigned short Bs[128][40];
  int tid = threadIdx.x;
  int lane = tid & 63, wave = tid >> 6;
  int wr = (wave >> 1) * 64, wc = (wave & 1) * 64;
  int l15 = lane & 15, lq = lane >> 4, kf = lq * 4;
  int brow = blockIdx.y * 128, bcol = blockIdx.x * 128;
  int arow = tid >> 2, akc = (tid & 3) * 8;
  f32x4 acc[4][4] = {};
  for (int kt = 0; kt < K / 32; kt++) {
    const unsigned short* Ag = A + (size_t)(brow + arow) * K + kt * 32 + akc;
    const unsigned short* Bg = BT + (size_t)(bcol + arow) * K + kt * 32 + akc;
    s16x8 a0 = *(const s16x8*)Ag;
    s16x8 a1 = *(const s16x8*)(Ag + (size_t)64 * K);
    s16x8 b0 = *(const s16x8*)Bg;
    s16x8 b1 = *(const s16x8*)(Bg + (size_t)64 * K);
    __syncthreads();
    *(s16x8*)&As[arow][akc] = a0;
    *(s16x8*)&As[arow + 64][akc] = a1;
    *(s16x8*)&Bs[arow][akc] = b0;
    *(s16x8*)&Bs[arow + 64][akc] = b1;
    __syncthreads();
    s16x8 af[4], bf[4];
#pragma unroll
    for (int m = 0; m < 4; m++) {
      s16x4 lo = *(const s16x4*)&As[wr + m * 16 + l15][kf];
      s16x4 hi = *(const s16x4*)&As[wr + m * 16 + l15][kf + 16];
      af[m] = __builtin_shufflevector(lo, hi, 0, 1, 2, 3, 4, 5, 6, 7);
      s16x4 blo = *(const s16x4*)&Bs[wc + m * 16 + l15][kf];
      s16x4 bhi = *(const s16x4*)&Bs[wc + m * 16 + l15][kf + 16];
      bf[m] = __builtin_shufflevector(blo, bhi, 0, 1, 2, 3, 4, 5, 6, 7);
    }
#pragma unroll
    for (int m = 0; m < 4; m++)
#pragma unroll
      for (int n = 0; n < 4; n++)
        acc[m][n] = __builtin_amdgcn_mfma_f32_16x16x32_bf16(af[m], bf[n], acc[m][n], 0, 0, 0);
  }
#pragma unroll
  for (int m = 0; m < 4; m++) {
#pragma unroll
    for (int n = 0; n < 4; n++) {
#pragma unroll
      for (int r = 0; r < 4; r++) {
        int grow = brow + wr + m * 16 + lq * 4 + r;
        int gcol = bcol + wc + n * 16 + l15;
        float v = acc[m][n][r];
        if (MODE != 0) v += bias[gcol];
        if (MODE == 0) {
          outF[(size_t)grow * N + gcol] = v;
        } else {
          int c = gcol;
          unsigned short* dst = outK;
          if (MODE == 2 && gcol >= 1152) { c = gcol - 1152; dst = outV; }
          int h = c / 72, d = c - h * 72;
          int t = grow >> 10, s = grow & 1023;
          dst[((size_t)((t * 16 + h) * 1024 + s)) * 96 + d] = f2b(v);
        }
      }
    }
  }
}

// ---------------- per-(row,head) RMSNorm in place, zero-fills pads ----------------
__global__ __launch_bounds__(64) void rmsnorm_kernel(unsigned short* __restrict__ buf,
                                                     const float* __restrict__ gamma) {
  int g = blockIdx.x;              // g = th*1024 + s
  int h = (g >> 10) & 15;
  size_t base = (size_t)g * 96;
  int l = threadIdx.x;
  float e0 = b2f(buf[base + l]);
  float e1 = 0.f;
  if (l < 8) e1 = b2f(buf[base + 64 + l]);
  float ss = e0 * e0 + e1 * e1;
#pragma unroll
  for (int m = 1; m < 64; m <<= 1) ss += __shfl_xor(ss, m);
  float sc = rsqrtf(ss * (1.0f / 72.0f) + 1e-6f);
  buf[base + l] = f2b(e0 * sc * gamma[h * 72 + l]);
  if (l < 32) {
    float v = 0.f;
    if (l < 8) v = e1 * sc * gamma[h * 72 + 64 + l];
    buf[base + 64 + l] = f2b(v);
  }
}

// ---------------- zero V padding cols 72..95 ----------------
__global__ __launch_bounds__(256) void zero_vpad_kernel(unsigned short* __restrict__ vn) {
  int i = blockIdx.x * 256 + threadIdx.x;  // 8*16*1024*24 total
  int row = i / 24, d = 72 + (i - row * 24);
  vn[(size_t)row * 96 + d] = 0;
}

// ---------------- flash attention per (t,h): S=QK^T, online softmax, O=PV ----------------
__global__ __launch_bounds__(256) void attn_kernel(const unsigned short* __restrict__ Qn,
                                                   const unsigned short* __restrict__ Kn,
                                                   const unsigned short* __restrict__ Vn,
                                                   unsigned short* __restrict__ att) {
  __shared__ unsigned short Kl[128][104];
  __shared__ unsigned short Vt[96][136];
  __shared__ unsigned short Pl[4][16][136];
  int tid = threadIdx.x;
  int lane = tid & 63, wave = tid >> 6;
  int l15 = lane & 15, lq = lane >> 4, kf = lq * 4;
  int qb = blockIdx.x, h = blockIdx.y, t = blockIdx.z;
  int th = t * 16 + h;
  const unsigned short* Q = Qn + (size_t)th * 1024 * 96;
  const unsigned short* Kp = Kn + (size_t)th * 1024 * 96;
  const unsigned short* Vp = Vn + (size_t)th * 1024 * 96;
  int qrow0 = qb * 64 + wave * 16;
  s16x8 qf[3];
#pragma unroll
  for (int c = 0; c < 3; c++) {
    const unsigned short* p = Q + (size_t)(qrow0 + l15) * 96 + c * 32 + kf;
    s16x4 lo = *(const s16x4*)p;
    s16x4 hi = *(const s16x4*)(p + 16);
    qf[c] = __builtin_shufflevector(lo, hi, 0, 1, 2, 3, 4, 5, 6, 7);
  }
  f32x4 o[5] = {};
  float mr[4], lr[4];
#pragma unroll
  for (int r = 0; r < 4; r++) { mr[r] = -3.0e38f; lr[r] = 0.f; }

  for (int kv0 = 0; kv0 < 1024; kv0 += 128) {
    __syncthreads();
#pragma unroll
    for (int i = 0; i < 6; i++) {
      int c = tid + i * 256;
      int row = c / 12, kc = c - row * 12;
      s16x8 k8 = *(const s16x8*)(Kp + (size_t)(kv0 + row) * 96 + kc * 8);
      *(s16x8*)&Kl[row][kc * 8] = k8;
      s16x8 v8 = *(const s16x8*)(Vp + (size_t)(kv0 + row) * 96 + kc * 8);
#pragma unroll
      for (int j = 0; j < 8; j++) Vt[kc * 8 + j][row] = (unsigned short)v8[j];
    }
    __syncthreads();
    // S = Q K^T  (D rows = q, cols = kv)
    f32x4 sf[8];
#pragma unroll
    for (int n = 0; n < 8; n++) {
      f32x4 a = {};
#pragma unroll
      for (int c = 0; c < 3; c++) {
        s16x4 lo = *(const s16x4*)&Kl[n * 16 + l15][c * 32 + kf];
        s16x4 hi = *(const s16x4*)&Kl[n * 16 + l15][c * 32 + kf + 16];
        s16x8 kfr = __builtin_shufflevector(lo, hi, 0, 1, 2, 3, 4, 5, 6, 7);
        a = __builtin_amdgcn_mfma_f32_16x16x32_bf16(qf[c], kfr, a, 0, 0, 0);
      }
      sf[n] = a;
    }
    // online softmax over this KV block
    float rmax[4];
#pragma unroll
    for (int r = 0; r < 4; r++) {
      float m = sf[0][r];
#pragma unroll
      for (int n = 1; n < 8; n++) m = fmaxf(m, sf[n][r]);
      m = fmaxf(m, __shfl_xor(m, 1));
      m = fmaxf(m, __shfl_xor(m, 2));
      m = fmaxf(m, __shfl_xor(m, 4));
      m = fmaxf(m, __shfl_xor(m, 8));
      rmax[r] = m;
    }
    float sc[4], rsum[4];
#pragma unroll
    for (int r = 0; r < 4; r++) {
      float mn = fmaxf(mr[r], rmax[r]);
      sc[r] = __expf(mr[r] - mn);
      mr[r] = mn;
      rsum[r] = 0.f;
    }
#pragma unroll
    for (int n = 0; n < 8; n++)
#pragma unroll
      for (int r = 0; r < 4; r++) {
        float p = __expf(sf[n][r] - mr[r]);
        sf[n][r] = p;
        rsum[r] += p;
      }
#pragma unroll
    for (int r = 0; r < 4; r++) {
      rsum[r] += __shfl_xor(rsum[r], 1);
      rsum[r] += __shfl_xor(rsum[r], 2);
      rsum[r] += __shfl_xor(rsum[r], 4);
      rsum[r] += __shfl_xor(rsum[r], 8);
      lr[r] = lr[r] * sc[r] + rsum[r];
    }
#pragma unroll
    for (int v = 0; v < 5; v++)
#pragma unroll
      for (int r = 0; r < 4; r++) o[v][r] *= sc[r];
    // P -> LDS (bf16), wave-private region
#pragma unroll
    for (int n = 0; n < 8; n++)
#pragma unroll
      for (int r = 0; r < 4; r++)
        Pl[wave][lq * 4 + r][n * 16 + l15] = f2b(sf[n][r]);
    __syncthreads();
    // O += P @ V
#pragma unroll
    for (int ks = 0; ks < 4; ks++) {
      s16x4 plo = *(const s16x4*)&Pl[wave][l15][ks * 32 + kf];
      s16x4 phi = *(const s16x4*)&Pl[wave][l15][ks * 32 + kf + 16];
      s16x8 pf = __builtin_shufflevector(plo, phi, 0, 1, 2, 3, 4, 5, 6, 7);
#pragma unroll
      for (int v = 0; v < 5; v++) {
        s16x4 vlo = *(const s16x4*)&Vt[v * 16 + l15][ks * 32 + kf];
        s16x4 vhi = *(const s16x4*)&Vt[v * 16 + l15][ks * 32 + kf + 16];
        s16x8 vf = __builtin_shufflevector(vlo, vhi, 0, 1, 2, 3, 4, 5, 6, 7);
        o[v] = __builtin_amdgcn_mfma_f32_16x16x32_bf16(pf, vf, o[v], 0, 0, 0);
      }
    }
  }
#pragma unroll
  for (int r = 0; r < 4; r++) {
    float inv = 1.0f / lr[r];
    int qrow = qrow0 + lq * 4 + r;
    size_t rowbase = (size_t)(t * 1024 + qrow) * 1152 + h * 72;
#pragma unroll
    for (int v = 0; v < 5; v++) {
      int d = v * 16 + l15;
      if (d < 72) att[rowbase + d] = f2b(o[v][r] * inv);
    }
  }
}

extern "C" void kernel_launch(void* const* d_in, const int* in_sizes, int n_in,
                              void* d_out, int out_size, void* d_ws, size_t ws_size,
                              hipStream_t stream) {
  const float* x   = (const float*)d_in[0];
  const float* Wq  = (const float*)d_in[1];
  const float* bq  = (const float*)d_in[2];
  const float* Wkv = (const float*)d_in[3];
  const float* bkv = (const float*)d_in[4];
  const float* qg  = (const float*)d_in[5];
  const float* kg  = (const float*)d_in[6];
  const float* Wo  = (const float*)d_in[7];
  float* out = (float*)d_out;

  char* w = (char*)d_ws;
  unsigned short* xb   = (unsigned short*)w; w += (size_t)8192 * 1152 * 2;   // 18.9 MB
  unsigned short* WqT  = (unsigned short*)w; w += (size_t)1152 * 1152 * 2;   // 2.65 MB
  unsigned short* WkvT = (unsigned short*)w; w += (size_t)2304 * 1152 * 2;   // 5.3 MB
  unsigned short* WoT  = (unsigned short*)w; w += (size_t)1152 * 1152 * 2;   // 2.65 MB
  unsigned short* qn   = (unsigned short*)w; w += (size_t)128 * 1024 * 96 * 2; // 25.2 MB
  unsigned short* kn   = (unsigned short*)w; w += (size_t)128 * 1024 * 96 * 2;
  unsigned short* vn   = (unsigned short*)w; w += (size_t)128 * 1024 * 96 * 2;
  unsigned short* att  = (unsigned short*)w; w += (size_t)8192 * 1152 * 2;

  cvt_bf16_kernel<<<4608, 256, 0, stream>>>(x, xb, 9437184 / 8);
  transpose_cvt_kernel<<<dim3(36, 36), dim3(32, 8), 0, stream>>>(Wq, WqT, 1152, 1152);
  transpose_cvt_kernel<<<dim3(72, 36), dim3(32, 8), 0, stream>>>(Wkv, WkvT, 1152, 2304);
  transpose_cvt_kernel<<<dim3(36, 36), dim3(32, 8), 0, stream>>>(Wo, WoT, 1152, 1152);

  gemm_bt_kernel<1><<<dim3(9, 64), 256, 0, stream>>>(xb, WqT, bq, 1152, nullptr, qn, nullptr);
  rmsnorm_kernel<<<131072, 64, 0, stream>>>(qn, qg);
  gemm_bt_kernel<2><<<dim3(18, 64), 256, 0, stream>>>(xb, WkvT, bkv, 2304, nullptr, kn, vn);
  rmsnorm_kernel<<<131072, 64, 0, stream>>>(kn, kg);
  zero_vpad_kernel<<<12288, 256, 0, stream>>>(vn);

  attn_kernel<<<dim3(16, 16, 8), 256, 0, stream>>>(qn, kn, vn, att);

  gemm_bt_kernel<0><<<dim3(9, 64), 256, 0, stream>>>(att, WoT, nullptr, 1152, out, nullptr, nullptr);
}

// Round 2
// 466.044 us; speedup vs baseline: 1.2671x; 1.2671x over previous
//
#include <hip/hip_runtime.h>

// SpatialAttention (QKNorm, no 1/sqrt(d)): B=1,T=8,S=1024,HID=1152,H=16,D=72
// Pipeline: cvt x->bf16 | W^T bf16 | GEMM1->q | rmsnorm q | GEMM2->k,v^T |
//           rmsnorm k | flash attn (swapped-QK^T, P in regs) | GEMM3 -> f32 out

typedef __attribute__((ext_vector_type(4))) short s16x4;
typedef __attribute__((ext_vector_type(8))) short s16x8;
typedef __attribute__((ext_vector_type(4))) float f32x4;

__device__ __forceinline__ unsigned short f2b(float x) {
  unsigned u = __float_as_uint(x);
  u += 0x7FFFu + ((u >> 16) & 1u);
  return (unsigned short)(u >> 16);
}
__device__ __forceinline__ float b2f(unsigned short u) {
  return __uint_as_float(((unsigned)u) << 16);
}

// ---------------- x -> bf16 ----------------
__global__ __launch_bounds__(256) void cvt_bf16_kernel(const float* __restrict__ in,
                                                       unsigned short* __restrict__ out,
                                                       int n8) {
  int i = blockIdx.x * 256 + threadIdx.x;
  if (i >= n8) return;
  const float4* p = (const float4*)(in + (size_t)i * 8);
  float4 a = p[0], b = p[1];
  s16x8 r;
  r[0] = (short)f2b(a.x); r[1] = (short)f2b(a.y); r[2] = (short)f2b(a.z); r[3] = (short)f2b(a.w);
  r[4] = (short)f2b(b.x); r[5] = (short)f2b(b.y); r[6] = (short)f2b(b.z); r[7] = (short)f2b(b.w);
  *(s16x8*)(out + (size_t)i * 8) = r;
}

// ---------------- W [K][N] f32 -> WT [N][K] bf16 ----------------
__global__ __launch_bounds__(256) void transpose_cvt_kernel(const float* __restrict__ W,
                                                            unsigned short* __restrict__ WT,
                                                            int K, int N) {
  __shared__ float tile[32][33];
  int n0 = blockIdx.x * 32, k0 = blockIdx.y * 32;
  int tx = threadIdx.x, ty = threadIdx.y;
#pragma unroll
  for (int i = 0; i < 4; i++)
    tile[ty + i * 8][tx] = W[(size_t)(k0 + ty + i * 8) * N + n0 + tx];
  __syncthreads();
#pragma unroll
  for (int i = 0; i < 4; i++)
    WT[(size_t)(n0 + ty + i * 8) * K + k0 + tx] = f2b(tile[tx][ty + i * 8]);
}

// ---------------- GEMM: C[M,N] = A[M,K] @ BT[N,K]^T (+bias) ----------------
// MODE 0: outF f32 row-major.  MODE 1: q -> outK bf16 [th][s][96].
// MODE 2: kv -> outK (col<1152) bf16 [th][s][96], V^T (col>=1152) -> outV bf16 [th][80][1024].
template <int MODE>
__global__ __launch_bounds__(256) void gemm_bt_kernel(const unsigned short* __restrict__ A,
                                                      const unsigned short* __restrict__ BT,
                                                      const float* __restrict__ bias, int N,
                                                      float* __restrict__ outF,
                                                      unsigned short* __restrict__ outK,
                                                      unsigned short* __restrict__ outV) {
  constexpr int K = 1152;
  __shared__ unsigned short As[128][40];
  __shared__ unsigned short Bs[128][40];
  int tid = threadIdx.x;
  int lane = tid & 63, wave = tid >> 6;
  int wr = (wave >> 1) * 64, wc = (wave & 1) * 64;
  int l15 = lane & 15, lq = lane >> 4, kf = lq * 4;
  int brow = blockIdx.y * 128, bcol = blockIdx.x * 128;
  int arow = tid >> 2, akc = (tid & 3) * 8;
  f32x4 acc[4][4] = {};
  for (int kt = 0; kt < K / 32; kt++) {
    const unsigned short* Ag = A + (size_t)(brow + arow) * K + kt * 32 + akc;
    const unsigned short* Bg = BT + (size_t)(bcol + arow) * K + kt * 32 + akc;
    s16x8 a0 = *(const s16x8*)Ag;
    s16x8 a1 = *(const s16x8*)(Ag + (size_t)64 * K);
    s16x8 b0 = *(const s16x8*)Bg;
    s16x8 b1 = *(const s16x8*)(Bg + (size_t)64 * K);
    __syncthreads();
    *(s16x8*)&As[arow][akc] = a0;
    *(s16x8*)&As[arow + 64][akc] = a1;
    *(s16x8*)&Bs[arow][akc] = b0;
    *(s16x8*)&Bs[arow + 64][akc] = b1;
    __syncthreads();
    s16x8 af[4], bf[4];
#pragma unroll
    for (int m = 0; m < 4; m++) {
      s16x4 lo = *(const s16x4*)&As[wr + m * 16 + l15][kf];
      s16x4 hi = *(const s16x4*)&As[wr + m * 16 + l15][kf + 16];
      af[m] = __builtin_shufflevector(lo, hi, 0, 1, 2, 3, 4, 5, 6, 7);
      s16x4 blo = *(const s16x4*)&Bs[wc + m * 16 + l15][kf];
      s16x4 bhi = *(const s16x4*)&Bs[wc + m * 16 + l15][kf + 16];
      bf[m] = __builtin_shufflevector(blo, bhi, 0, 1, 2, 3, 4, 5, 6, 7);
    }
#pragma unroll
    for (int m = 0; m < 4; m++)
#pragma unroll
      for (int n = 0; n < 4; n++)
        acc[m][n] = __builtin_amdgcn_mfma_f32_16x16x32_bf16(af[m], bf[n], acc[m][n], 0, 0, 0);
  }
#pragma unroll
  for (int m = 0; m < 4; m++) {
#pragma unroll
    for (int n = 0; n < 4; n++) {
#pragma unroll
      for (int r = 0; r < 4; r++) {
        int grow = brow + wr + m * 16 + lq * 4 + r;
        int gcol = bcol + wc + n * 16 + l15;
        float v = acc[m][n][r];
        if (MODE != 0) v += bias[gcol];
        if (MODE == 0) {
          outF[(size_t)grow * N + gcol] = v;
        } else {
          int t = grow >> 10, s = grow & 1023;
          if (MODE == 2 && gcol >= 1152) {
            int c = gcol - 1152;
            int h = c / 72, d = c - h * 72;
            outV[((size_t)((t * 16 + h) * 80 + d)) * 1024 + s] = f2b(v);
          } else {
            int h = gcol / 72, d = gcol - h * 72;
            outK[((size_t)((t * 16 + h) * 1024 + s)) * 96 + d] = f2b(v);
          }
        }
      }
    }
  }
}

// ---------------- per-(row,head) RMSNorm in place, zero-fills pads ----------------
__global__ __launch_bounds__(64) void rmsnorm_kernel(unsigned short* __restrict__ buf,
                                                     const float* __restrict__ gamma) {
  int g = blockIdx.x;              // g = th*1024 + s
  int h = (g >> 10) & 15;
  size_t base = (size_t)g * 96;
  int l = threadIdx.x;
  float e0 = b2f(buf[base + l]);
  float e1 = 0.f;
  if (l < 8) e1 = b2f(buf[base + 64 + l]);
  float ss = e0 * e0 + e1 * e1;
#pragma unroll
  for (int m = 1; m < 64; m <<= 1) ss += __shfl_xor(ss, m);
  float sc = rsqrtf(ss * (1.0f / 72.0f) + 1e-6f);
  buf[base + l] = f2b(e0 * sc * gamma[h * 72 + l]);
  if (l < 32) {
    float v = 0.f;
    if (l < 8) v = e1 * sc * gamma[h * 72 + 64 + l];
    buf[base + 64 + l] = f2b(v);
  }
}

// ---------------- flash attention: swapped QK^T, P stays in registers ----------------
// Qn,Kn: [th][1024][96] bf16 (pads zeroed). VtG: [th][80][1024] bf16 (rows 72..79 garbage,
// pollutes only unstored d>=72 outputs). att: [8192][1152] bf16.
__global__ __launch_bounds__(256) void attn_kernel(const unsigned short* __restrict__ Qn,
                                                   const unsigned short* __restrict__ Kn,
                                                   const unsigned short* __restrict__ VtG,
                                                   unsigned short* __restrict__ att) {
  __shared__ unsigned short Kl[64][100];   // pad 100: bank = 18*l15 mod 32, all-distinct
  __shared__ unsigned short Vt[80][76];    // pad 76:  bank = 6*l15 mod 32, all-distinct
  int tid = threadIdx.x;
  int lane = tid & 63, wave = tid >> 6;
  int l15 = lane & 15, lq = lane >> 4, kf = lq * 4;
  // bijective XCD swizzle: nwg=2048, 2048%8==0
  int bid = blockIdx.x;
  int orig = (bid & 7) * 256 + (bid >> 3);
  int qb = orig & 15, th = orig >> 4;
  int t = th >> 4, h = th & 15;
  const unsigned short* Q = Qn + (size_t)th * 1024 * 96;
  const unsigned short* Kp = Kn + (size_t)th * 1024 * 96;
  const unsigned short* Vg = VtG + (size_t)th * 80 * 1024;
  int qrow0 = qb * 64 + wave * 16;
  // Q fragments (B-operand: col=l15=q, k=d)
  s16x8 qf[3];
#pragma unroll
  for (int c = 0; c < 3; c++) {
    const unsigned short* p = Q + (size_t)(qrow0 + l15) * 96 + c * 32 + kf;
    s16x4 lo = *(const s16x4*)p;
    s16x4 hi = *(const s16x4*)(p + 16);
    qf[c] = __builtin_shufflevector(lo, hi, 0, 1, 2, 3, 4, 5, 6, 7);
  }
  f32x4 o[5] = {};          // O[q=4lq+r][d=l15+16v]
  float m_r = -3.0e38f, l_r = 0.f;   // per-lane state for q = l15

  for (int kv0 = 0; kv0 < 1024; kv0 += 64) {
    __syncthreads();
    // stage K tile (64x96, 768 s16x8 chunks) + V^T tile (80x64, 640 chunks)
#pragma unroll
    for (int i = 0; i < 6; i++) {
      int c = tid + i * 256;
      if (c < 768) {
        int row = c / 12, co = c - row * 12;
        s16x8 k8 = *(const s16x8*)(Kp + (size_t)(kv0 + row) * 96 + co * 8);
        *(s16x8*)&Kl[row][co * 8] = k8;
      } else if (c < 1408) {
        int cc = c - 768;
        int d = cc >> 3, co = cc & 7;
        s16x8 v8 = *(const s16x8*)(Vg + (size_t)d * 1024 + kv0 + co * 8);
        *(s16x8*)&Vt[d][co * 8] = v8;
      }
    }
    __syncthreads();
    // S^T = mfma(K, Q): st[n][r] = S[q=l15][kv = n*16 + 4*lq + r]
    f32x4 st[4];
#pragma unroll
    for (int n = 0; n < 4; n++) {
      f32x4 a = {};
#pragma unroll
      for (int c = 0; c < 3; c++) {
        s16x4 lo = *(const s16x4*)&Kl[n * 16 + l15][c * 32 + kf];
        s16x4 hi = *(const s16x4*)&Kl[n * 16 + l15][c * 32 + kf + 16];
        s16x8 kfr = __builtin_shufflevector(lo, hi, 0, 1, 2, 3, 4, 5, 6, 7);
        a = __builtin_amdgcn_mfma_f32_16x16x32_bf16(kfr, qf[c], a, 0, 0, 0);
      }
      st[n] = a;
    }
    // online softmax for q = l15 (reduce over kv: 16 local + lq-group shfl)
    float tmax = st[0][0];
#pragma unroll
    for (int n = 0; n < 4; n++)
#pragma unroll
      for (int r = 0; r < 4; r++) tmax = fmaxf(tmax, st[n][r]);
    tmax = fmaxf(tmax, __shfl_xor(tmax, 16));
    tmax = fmaxf(tmax, __shfl_xor(tmax, 32));
    float mn = fmaxf(m_r, tmax);
    float scale = __expf(m_r - mn);
    m_r = mn;
    float sum = 0.f;
#pragma unroll
    for (int n = 0; n < 4; n++)
#pragma unroll
      for (int r = 0; r < 4; r++) {
        float p = __expf(st[n][r] - mn);
        st[n][r] = p;
        sum += p;
      }
    sum += __shfl_xor(sum, 16);
    sum += __shfl_xor(sum, 32);
    l_r = l_r * scale + sum;
    // rescale O (scale for q=4lq+r lives at lane 4lq+r)
#pragma unroll
    for (int r = 0; r < 4; r++) {
      float scq = __shfl(scale, 4 * lq + r);
#pragma unroll
      for (int v = 0; v < 5; v++) o[v][r] *= scq;
    }
    // P fragments directly from st registers (A-operand: row=l15=q, k=kv)
#pragma unroll
    for (int b = 0; b < 2; b++) {
      s16x8 pf;
#pragma unroll
      for (int j = 0; j < 8; j++) pf[j] = (short)f2b(st[2 * b + (j >> 2)][j & 3]);
#pragma unroll
      for (int v = 0; v < 5; v++) {
        s16x4 vlo = *(const s16x4*)&Vt[v * 16 + l15][b * 32 + kf];
        s16x4 vhi = *(const s16x4*)&Vt[v * 16 + l15][b * 32 + kf + 16];
        s16x8 vf = __builtin_shufflevector(vlo, vhi, 0, 1, 2, 3, 4, 5, 6, 7);
        o[v] = __builtin_amdgcn_mfma_f32_16x16x32_bf16(pf, vf, o[v], 0, 0, 0);
      }
    }
  }
  // epilogue: normalize by l (lives at lane 4lq+r), store d<72
#pragma unroll
  for (int r = 0; r < 4; r++) {
    float inv = 1.0f / __shfl(l_r, 4 * lq + r);
    int qrow = qrow0 + 4 * lq + r;
    size_t rowbase = (size_t)(t * 1024 + qrow) * 1152 + h * 72;
#pragma unroll
    for (int v = 0; v < 5; v++) {
      int d = v * 16 + l15;
      if (d < 72) att[rowbase + d] = f2b(o[v][r] * inv);
    }
  }
}

extern "C" void kernel_launch(void* const* d_in, const int* in_sizes, int n_in,
                              void* d_out, int out_size, void* d_ws, size_t ws_size,
                              hipStream_t stream) {
  const float* x   = (const float*)d_in[0];
  const float* Wq  = (const float*)d_in[1];
  const float* bq  = (const float*)d_in[2];
  const float* Wkv = (const float*)d_in[3];
  const float* bkv = (const float*)d_in[4];
  const float* qg  = (const float*)d_in[5];
  const float* kg  = (const float*)d_in[6];
  const float* Wo  = (const float*)d_in[7];
  float* out = (float*)d_out;

  char* w = (char*)d_ws;
  unsigned short* xb   = (unsigned short*)w; w += (size_t)8192 * 1152 * 2;     // 18.9 MB
  unsigned short* WqT  = (unsigned short*)w; w += (size_t)1152 * 1152 * 2;     // 2.65 MB
  unsigned short* WkvT = (unsigned short*)w; w += (size_t)2304 * 1152 * 2;     // 5.3 MB
  unsigned short* WoT  = (unsigned short*)w; w += (size_t)1152 * 1152 * 2;     // 2.65 MB
  unsigned short* qn   = (unsigned short*)w; w += (size_t)128 * 1024 * 96 * 2; // 25.2 MB
  unsigned short* kn   = (unsigned short*)w; w += (size_t)128 * 1024 * 96 * 2; // 25.2 MB
  unsigned short* vt   = (unsigned short*)w; w += (size_t)128 * 80 * 1024 * 2; // 21.0 MB
  unsigned short* att  = (unsigned short*)w; w += (size_t)8192 * 1152 * 2;     // 18.9 MB

  cvt_bf16_kernel<<<4608, 256, 0, stream>>>(x, xb, 9437184 / 8);
  transpose_cvt_kernel<<<dim3(36, 36), dim3(32, 8), 0, stream>>>(Wq, WqT, 1152, 1152);
  transpose_cvt_kernel<<<dim3(72, 36), dim3(32, 8), 0, stream>>>(Wkv, WkvT, 1152, 2304);
  transpose_cvt_kernel<<<dim3(36, 36), dim3(32, 8), 0, stream>>>(Wo, WoT, 1152, 1152);

  gemm_bt_kernel<1><<<dim3(9, 64), 256, 0, stream>>>(xb, WqT, bq, 1152, nullptr, qn, nullptr);
  rmsnorm_kernel<<<131072, 64, 0, stream>>>(qn, qg);
  gemm_bt_kernel<2><<<dim3(18, 64), 256, 0, stream>>>(xb, WkvT, bkv, 2304, nullptr, kn, vt);
  rmsnorm_kernel<<<131072, 64, 0, stream>>>(kn, kg);

  attn_kernel<<<2048, 256, 0, stream>>>(qn, kn, vt, att);

  gemm_bt_kernel<0><<<dim3(9, 64), 256, 0, stream>>>(att, WoT, nullptr, 1152, out, nullptr, nullptr);
}